// Round 13
// baseline (492.440 us; speedup 1.0000x reference)
//
#include <hip/hip_runtime.h>
#include <hip/hip_bf16.h>

// AdaptiveReLULayer: out[b,n,o] = leaky( sum_i x[b,n,i] * weight[idx[b],i,o] + bias[o], 0.2 )
// B=2048, N=256, IN=256, OUT=256, C=1024.  f32 I/O; bf16 MFMA, f32 accum.
//
// R15 vs R11 (248us best) / R14 (272us, fabric-halving refuted):
// R11 decomposition: HBM floor 170us; measured 4.3 of 6.3 TB/s.  Per block,
// HBM activity (x at birth, out at death) covers ~55% of lifetime -> block-
// level DUTY-CYCLE deficit.  Prior duty attacks failed for mechanical
// reasons (R10: conflicts+starvation; R13/14: collapse / lost overlap).
// R15 tests the theory clean: PERSISTENT blocks, grid=256 (1/CU, 96KB LDS),
// each sweeping 32 consecutive 64r x 256o tiles with R11's exact per-tile
// machinery (bbyte zero-conflict B, depth-2 named rb sets + anti-sinking,
// per-round lgkm+barrier, nt x/out).  New: next tile's x panel prefetched in
// 4 reg bursts (xa[4]=16 regs) spread across the current tile's rounds
// (issue@t=0,2,4,6 -> flush@t+2; slack >= 1 round ~ 1900cy >> 900cy HBM),
// and the B stream runs continuously across tile boundaries (all set/parity
// indices compile-time in the unrolled t-loop).  Every CU issues HBM loads
// every round; stores drain continuously -> duty ~ 1 by construction.
// Pre-committed: VGPR 150-220 (<130 void); FETCH ~537MB; WRITE ~524MB;
// conflicts ~0; predict 200-225us if duty-cycle binds; >=260 -> revert R11
// and declare the service wall.

#define BK 32

typedef __attribute__((ext_vector_type(8))) __bf16 bf16x8;
typedef __attribute__((ext_vector_type(4))) float f32x4;
typedef __attribute__((ext_vector_type(4))) unsigned int u32x4;
typedef __attribute__((ext_vector_type(2))) unsigned int u32x2;

#define B_LDS 65536   // B^T dbuf base (A dbuf occupies 0..65535)

__device__ __forceinline__ f32x4 MFMA(u32x4 a, u32x4 b, f32x4 c) {
    return __builtin_amdgcn_mfma_f32_16x16x32_bf16(
        __builtin_bit_cast(bf16x8, a), __builtin_bit_cast(bf16x8, b), c, 0, 0, 0);
}

__device__ __forceinline__ unsigned pk2(float a, float b) {
    __hip_bfloat16 ha = __float2bfloat16(a);
    __hip_bfloat16 hb = __float2bfloat16(b);
    unsigned short sa, sb;
    __builtin_memcpy(&sa, &ha, 2);
    __builtin_memcpy(&sb, &hb, 2);
    return (unsigned)sa | ((unsigned)sb << 16);
}

// B^T tile byte offset for (o 0..255, p 0..31): 128 row-pairs x 128B.
// R7/R11-measured ZERO bank conflicts for these read/write shapes.
__device__ __forceinline__ int bbyte(int o, int p) {
    const int rp  = o >> 1;
    const int raw = ((o & 1) << 2) | (p >> 3);
    const int key = (rp ^ (o >> 4)) & 7;
    return rp * 128 + ((raw ^ key) << 4) + ((p & 7) << 1);
}

__global__ __launch_bounds__(256) void argemm_kernel(
    const float* __restrict__ x,
    const int* __restrict__ idx,
    const float* __restrict__ w,
    const float* __restrict__ bias,
    float* __restrict__ out)
{
    __shared__ __align__(16) char lds[98304];  // A dbuf 2x32KB | B^T dbuf 2x16KB

    const int tid = threadIdx.x;
    const int l   = tid & 63;
    const int wid = tid >> 6;
    const int wr  = wid >> 1;   // 32-row half of the 64-row tile
    const int wc  = wid & 1;    // 128-col half

    const int p = (int)blockIdx.x;   // persistent block, 1 per CU

    const int g = l >> 4;   // 0..3 (k-subgroup)
    const int i = l & 15;   // 0..15

    // tile index helpers: global tile gt = p*32 + j
    auto bOf  = [&](int j) { return (p * 32 + j) >> 2; };
    auto n0Of = [&](int j) { return ((p * 32 + j) & 3) * 64; };

    // ---- B staging maps (R11 verbatim) ----
    const int q   = tid & 63;        // o-quad: cols q*4 .. q*4+3
    const int oct = tid >> 6;        // p-octet: p = oct*8 .. oct*8+7
    const size_t wpoff = (size_t)(oct * 8) * 256 + q * 4;
    int bW[4];
#pragma unroll
    for (int j = 0; j < 4; ++j)
        bW[j] = bbyte(q * 4 + j, oct * 8);

    // ---- fragment read addresses (R11 shapes) ----
    int bR[8];
#pragma unroll
    for (int n = 0; n < 8; ++n)
        bR[n] = bbyte(wc * 128 + n * 16 + i, g * 8);
    int aRow[2], aKey[2];
#pragma unroll
    for (int m = 0; m < 2; ++m) {
        const int r = wr * 32 + m * 16 + i;
        aRow[m] = r * 512;
        aKey[m] = r & 31;
    }
    const int csw = l >> 1;          // A staging k-chunk of this lane
    const int sub = (l & 1) * 8;

    float biasf[8];
#pragma unroll
    for (int n = 0; n < 8; ++n)
        biasf[n] = bias[wc * 128 + n * 16 + i];

    // ---- streaming pointers ----
    const float* wp_cur  = w + (size_t)idx[bOf(0)] * 65536 + wpoff;
    const float* wp_next = w + (size_t)idx[bOf(1)] * 65536 + wpoff;
    const float* xg_next = x + (size_t)bOf(1) * 65536
                           + (size_t)(n0Of(1) + wid * 16) * 256 + l * 4;

    // ---- named staging sets ----
    f32x4 rb[2][8];   // B: [set][e], k-row = T*32 + oct*8 + e
    f32x4 xa[4];      // A prefetch burst (4 rows/wave/burst)

    auto issueB = [&](const float* wp, int tt, int s) {
#pragma unroll
        for (int e = 0; e < 8; ++e)
            rb[s][e] = *(const f32x4*)(wp + (size_t)(tt * BK + e) * 256);
    };
    auto flushB = [&](int s) {        // writes B_lds[s] from rb[s]
        char* base = (char*)lds + B_LDS + s * 16384;
#pragma unroll
        for (int j = 0; j < 4; ++j) {
            u32x4 pq;
            pq.x = pk2(rb[s][0][j], rb[s][1][j]);
            pq.y = pk2(rb[s][2][j], rb[s][3][j]);
            pq.z = pk2(rb[s][4][j], rb[s][5][j]);
            pq.w = pk2(rb[s][6][j], rb[s][7][j]);
            *(u32x4*)(base + bW[j]) = pq;
        }
    };
    auto issueA = [&](int k) {        // burst k: rows wid*16 + k*4 .. +3
#pragma unroll
        for (int j2 = 0; j2 < 4; ++j2)
            xa[j2] = __builtin_nontemporal_load(
                (const f32x4*)(xg_next + (k * 4 + j2) * 256));
    };
    auto flushA = [&](int k, char* An) {
#pragma unroll
        for (int j2 = 0; j2 < 4; ++j2) {
            const int r = wid * 16 + k * 4 + j2;
            u32x2 pr;
            pr.x = pk2(xa[j2].x, xa[j2].y);
            pr.y = pk2(xa[j2].z, xa[j2].w);
            *(u32x2*)(An + r * 512 + ((csw ^ (r & 31)) << 4) + sub) = pr;
        }
    };

    // ---- prologue: B T=0,1 in flight; panel 0 -> A_lds[0]; flush B0; B2 ----
    issueB(wp_cur, 0, 0);
    __builtin_amdgcn_sched_barrier(0);
    issueB(wp_cur, 1, 1);
    __builtin_amdgcn_sched_barrier(0);
    {
        const float* xw = x + (size_t)bOf(0) * 65536
                          + (size_t)(n0Of(0) + wid * 16) * 256 + l * 4;
        f32x4 t8[8];
#pragma unroll
        for (int s2 = 0; s2 < 2; ++s2) {
#pragma unroll
            for (int j = 0; j < 8; ++j)
                t8[j] = __builtin_nontemporal_load(
                    (const f32x4*)(xw + (s2 * 8 + j) * 256));
            __builtin_amdgcn_sched_barrier(0);
#pragma unroll
            for (int j = 0; j < 8; ++j) {
                const int r = wid * 16 + s2 * 8 + j;
                u32x2 pr;
                pr.x = pk2(t8[j].x, t8[j].y);
                pr.y = pk2(t8[j].z, t8[j].w);
                *(u32x2*)((char*)lds + r * 512 + ((csw ^ (r & 31)) << 4) + sub) = pr;
            }
        }
    }
    flushB(0);
    issueB(wp_cur, 2, 0);
    __builtin_amdgcn_sched_barrier(0);
    asm volatile("s_waitcnt lgkmcnt(0)" ::: "memory");
    __builtin_amdgcn_sched_barrier(0);
    __builtin_amdgcn_s_barrier();

    f32x4 acc[2][8];
#pragma unroll
    for (int m = 0; m < 2; ++m)
#pragma unroll
        for (int n = 0; n < 8; ++n)
            acc[m][n] = (f32x4){0.f, 0.f, 0.f, 0.f};

    // ---- persistent tile loop ----
    for (int j = 0; j < 32; ++j) {
        char* Ac = (char*)lds + (j & 1) * 32768;        // current A panel
        char* An = (char*)lds + ((j & 1) ^ 1) * 32768;  // next A panel
        const bool haveNext = (j < 31);

#pragma unroll
        for (int t = 0; t < 8; ++t) {
            const char* bbuf = (const char*)lds + B_LDS + (t & 1) * 16384;

            u32x4 af[2];
#pragma unroll
            for (int m = 0; m < 2; ++m)
                af[m] = *(const u32x4*)(Ac + aRow[m]
                                        + (((t * 4 + g) ^ aKey[m]) << 4));
#pragma unroll
            for (int n = 0; n < 8; ++n) {
                const u32x4 bq = *(const u32x4*)(bbuf + bR[n]);
#pragma unroll
                for (int m = 0; m < 2; ++m)
                    acc[m][n] = MFMA(af[m], bq, acc[m][n]);
            }

            // ---- continuous B stream (T = j*8 + t) ----
            if (t < 7 || haveNext)
                flushB((t + 1) & 1);                    // tile T+1 -> buf/set (t+1)&1
            if (t < 5)
                issueB(wp_cur, t + 3, (t + 1) & 1);     // T+3 within tile j
            else if (haveNext)
                issueB(wp_next, t - 5, (t + 1) & 1);    // T+3 in tile j+1
            __builtin_amdgcn_sched_barrier(0);

            // ---- spread A prefetch for tile j+1 ----
            if (haveNext) {
                if (t == 2) flushA(0, An);
                if (t == 4) flushA(1, An);
                if (t == 6) flushA(2, An);
                if (t == 7) flushA(3, An);
                if (t == 0) issueA(0);
                if (t == 2) issueA(1);
                if (t == 4) issueA(2);
                if (t == 6) issueA(3);
                __builtin_amdgcn_sched_barrier(0);
            }

            // ---- tile epilogue at t==7: stores + acc reset ----
            if (t == 7) {
                const int n0 = n0Of(j);
                float* ob = out + (size_t)bOf(j) * 65536;
#pragma unroll
                for (int m = 0; m < 2; ++m)
#pragma unroll
                    for (int r = 0; r < 4; ++r) {
                        const int row = n0 + wr * 32 + m * 16 + g * 4 + r;
#pragma unroll
                        for (int n = 0; n < 8; ++n) {
                            float v = acc[m][n][r] + biasf[n];
                            v = (v >= 0.f) ? v : 0.2f * v;
                            __builtin_nontemporal_store(
                                v, &ob[row * 256 + wc * 128 + n * 16 + i]);
                        }
                    }
#pragma unroll
                for (int m = 0; m < 2; ++m)
#pragma unroll
                    for (int n = 0; n < 8; ++n)
                        acc[m][n] = (f32x4){0.f, 0.f, 0.f, 0.f};
            }

            asm volatile("s_waitcnt lgkmcnt(0)" ::: "memory");
            __builtin_amdgcn_sched_barrier(0);
            __builtin_amdgcn_s_barrier();
        }

        // ---- advance stream pointers ----
        wp_cur = wp_next;
        if (j + 2 < 32) {
            wp_next = w + (size_t)idx[bOf(j + 2)] * 65536 + wpoff;
            xg_next = x + (size_t)bOf(j + 2) * 65536
                      + (size_t)(n0Of(j + 2) + wid * 16) * 256 + l * 4;
        }
    }
}

extern "C" void kernel_launch(void* const* d_in, const int* in_sizes, int n_in,
                              void* d_out, int out_size, void* d_ws, size_t ws_size,
                              hipStream_t stream) {
    const float* x    = (const float*)d_in[0];
    const int*   idx  = (const int*)d_in[1];
    const float* w    = (const float*)d_in[2];
    const float* bias = (const float*)d_in[3];
    float*       out  = (float*)d_out;
    (void)d_ws; (void)ws_size; (void)n_in; (void)out_size;

    dim3 grid(256), block(256);   // persistent: 1 block per CU, 32 tiles each
    hipLaunchKernelGGL(argemm_kernel, grid, block, 0, stream, x, idx, w, bias, out);
}

// Round 14
// 302.936 us; speedup vs baseline: 1.6256x; 1.6256x over previous
//
#include <hip/hip_runtime.h>
#include <hip/hip_bf16.h>

// AdaptiveReLULayer: out[b,n,o] = leaky( sum_i x[b,n,i] * weight[idx[b],i,o] + bias[o], 0.2 )
// B=2048, N=256, IN=256, OUT=256, C=1024.  f32 I/O; bf16 MFMA, f32 accum.
//
// R16 vs R11 (248us best) / R15 (492us, persistent blocks broke w's L3
// time-locality: FETCH 537MB -> 1.29GB):
// last untested lever: TLP at the proven operating point.  R11 = 4-wave
// blocks, 2 blocks/CU = 8 waves/CU (2/SIMD) -- thin for latency hiding.
// R16: SAME 64r x 256o tile, SAME 64KB LDS, SAME machinery, 512-thread
// blocks -> 16 waves/CU (4/SIMD), per-wave work halved:
//   * 8 waves: (wr 0..3 = 16-row strip, wc 0..1 = 128-col half); acc[8]
//     (32 VGPR) -> total VGPR ~110 < 128 naturally (no launch-bounds cap,
//     no R12 trap); 2 blocks/CU preserved.
//   * B staging: waves 0..3 ONLY, R11/R13-conflict-verified (0.0 measured)
//     256-thread bbyte map verbatim; depth-2 named rb sets + anti-sinking.
//   * A staging: all 8 waves, 8 rows each (R13-verified 0-conflict shape).
//   * launch-ordered swarm + XCD swizzle kept (R15 lesson: w L3 residency
//     requires swarm time-correlation); nt x-loads / out-stores kept;
//     64-row store tile kept (only WRITE-clean shape).
// Pre-committed: VGPR 100-126 (>128 or <=70 void); FETCH ~537MB; WRITE
// ~524MB; conflicts ~0; predict 210-230us if TLP binds; flat -> declare
// service wall; >=260 -> revert R11.

#define BK 32

typedef __attribute__((ext_vector_type(8))) __bf16 bf16x8;
typedef __attribute__((ext_vector_type(4))) float f32x4;
typedef __attribute__((ext_vector_type(4))) unsigned int u32x4;
typedef __attribute__((ext_vector_type(2))) unsigned int u32x2;

#define B_LDS 32768   // B^T dbuf base (A panel occupies 0..32767)

__device__ __forceinline__ f32x4 MFMA(u32x4 a, u32x4 b, f32x4 c) {
    return __builtin_amdgcn_mfma_f32_16x16x32_bf16(
        __builtin_bit_cast(bf16x8, a), __builtin_bit_cast(bf16x8, b), c, 0, 0, 0);
}

__device__ __forceinline__ unsigned pk2(float a, float b) {
    __hip_bfloat16 ha = __float2bfloat16(a);
    __hip_bfloat16 hb = __float2bfloat16(b);
    unsigned short sa, sb;
    __builtin_memcpy(&sa, &ha, 2);
    __builtin_memcpy(&sb, &hb, 2);
    return (unsigned)sa | ((unsigned)sb << 16);
}

// B^T tile byte offset for (o 0..255, p 0..31): 128 row-pairs x 128B.
// R7/R13-measured ZERO bank conflicts for these read/write shapes.
__device__ __forceinline__ int bbyte(int o, int p) {
    const int rp  = o >> 1;
    const int raw = ((o & 1) << 2) | (p >> 3);
    const int key = (rp ^ (o >> 4)) & 7;
    return rp * 128 + ((raw ^ key) << 4) + ((p & 7) << 1);
}

__global__ __launch_bounds__(512) void argemm_kernel(
    const float* __restrict__ x,
    const int* __restrict__ idx,
    const float* __restrict__ w,
    const float* __restrict__ bias,
    float* __restrict__ out)
{
    __shared__ __align__(16) char lds[65536];  // A panel 32KB | B^T dbuf 2x16KB

    const int tid = threadIdx.x;
    const int l   = tid & 63;
    const int wid = tid >> 6;   // 0..7
    const int wr  = wid >> 1;   // 16-row strip of the 64-row tile
    const int wc  = wid & 1;    // 128-col half

    // XCD-chunked swizzle: the 4 row-tiles of one b are logically adjacent ->
    // same XCD, co-temporal -> w panel L2/L3-coincident (R15 lesson).
    const unsigned bid     = blockIdx.x;
    const unsigned chunk   = gridDim.x >> 3;
    const unsigned logical = (bid & 7u) * chunk + (bid >> 3);
    const int b  = (int)(logical >> 2);
    const int n0 = (int)(logical & 3u) * 64;

    const int g = l >> 4;   // 0..3 (k-subgroup)
    const int i = l & 15;   // 0..15

    const int c = idx[b];
    const float* xb = x + (size_t)b * (256 * 256);
    const float* wb = w + (size_t)c * (256 * 256);

    // ---- B staging maps (R11 verbatim; ACTIVE ONLY FOR WAVES 0..3) ----
    const int q   = tid & 63;        // o-quad: cols q*4 .. q*4+3
    const int oct = tid >> 6;        // p-octet (valid 0..3 when wid<4)
    const float* wp = wb + (size_t)(oct * 8) * 256 + q * 4;
    int bW[4];
#pragma unroll
    for (int j = 0; j < 4; ++j)
        bW[j] = bbyte(q * 4 + j, (oct & 3) * 8);

    // ---- fragment read addresses ----
    int bR[8];
#pragma unroll
    for (int n = 0; n < 8; ++n)
        bR[n] = bbyte(wc * 128 + n * 16 + i, g * 8);
    const int aRow = (wr * 16 + i) * 512;
    const int aKey = (wr * 16 + i) & 31;

    // ---- two named B staging sets: tile T -> set T&1 (waves 0..3) ----
    f32x4 rb[2][8];   // [set][e]: k-row = T*32 + oct*8 + e

    auto issueB = [&](int t, int s) {
#pragma unroll
        for (int e = 0; e < 8; ++e)
            rb[s][e] = *(const f32x4*)(wp + (size_t)(t * BK + e) * 256);
    };
    auto flushB = [&](int T, int s) {
        char* base = (char*)lds + B_LDS + (T & 1) * 16384;
#pragma unroll
        for (int j = 0; j < 4; ++j) {
            u32x4 pq;                                   // 8 bf16, p ascending
            pq.x = pk2(rb[s][0][j], rb[s][1][j]);
            pq.y = pk2(rb[s][2][j], rb[s][3][j]);
            pq.z = pk2(rb[s][4][j], rb[s][5][j]);
            pq.w = pk2(rb[s][6][j], rb[s][7][j]);
            *(u32x4*)(base + bW[j]) = pq;
        }
    };

    // ---- prologue: B tiles 0,1 in flight (waves 0..3); A panel staged ----
    if (wid < 4) {
        issueB(0, 0);
        __builtin_amdgcn_sched_barrier(0);
        issueB(1, 1);
        __builtin_amdgcn_sched_barrier(0);
    }

    // A: each wave stages rows wid*8 .. wid*8+7, one full 1KB row per instr.
    {
        const float* xw = xb + (n0 + wid * 8) * 256 + l * 4;
        const int csw = l >> 1;
        const int sub = (l & 1) * 8;
        f32x4 xa[8];
#pragma unroll
        for (int j = 0; j < 8; ++j)
            xa[j] = __builtin_nontemporal_load((const f32x4*)(xw + j * 256));
        __builtin_amdgcn_sched_barrier(0);
#pragma unroll
        for (int j = 0; j < 8; ++j) {
            const int r = wid * 8 + j;
            u32x2 p;
            p.x = pk2(xa[j].x, xa[j].y);
            p.y = pk2(xa[j].z, xa[j].w);
            *(u32x2*)((char*)lds + r * 512 + ((csw ^ (r & 31)) << 4) + sub) = p;
        }
    }

    if (wid < 4) {
        flushB(0, 0);
        issueB(2, 0);
        __builtin_amdgcn_sched_barrier(0);
    }
    asm volatile("s_waitcnt lgkmcnt(0)" ::: "memory");
    __builtin_amdgcn_sched_barrier(0);
    __builtin_amdgcn_s_barrier();

    f32x4 acc[8];
#pragma unroll
    for (int n = 0; n < 8; ++n)
        acc[n] = (f32x4){0.f, 0.f, 0.f, 0.f};

    // ---- K loop: 8 rounds (R11 skeleton; 8 MFMA/wave/round) ----
#pragma unroll
    for (int t = 0; t < 8; ++t) {
        const char* bbuf = (const char*)lds + B_LDS + (t & 1) * 16384;

        const u32x4 af = *(const u32x4*)((const char*)lds + aRow
                                         + (((t * 4 + g) ^ aKey) << 4));
#pragma unroll
        for (int n = 0; n < 8; ++n) {
            const u32x4 bq = *(const u32x4*)(bbuf + bR[n]);
            acc[n] = MFMA(af, bq, acc[n]);
        }

        if (t < 7) {
            if (wid < 4) {
                flushB(t + 1, (t + 1) & 1);   // loads issued 2 rounds ago
                if (t < 5) {
                    issueB(t + 3, (t + 1) & 1);
                    __builtin_amdgcn_sched_barrier(0);   // forbid load sinking
                }
            }
            asm volatile("s_waitcnt lgkmcnt(0)" ::: "memory");
            __builtin_amdgcn_sched_barrier(0);
            __builtin_amdgcn_s_barrier();
        }
    }

    // ---- epilogue: bias + LeakyReLU(0.2), nontemporal f32 store ----
    float biasf[8];
#pragma unroll
    for (int n = 0; n < 8; ++n)
        biasf[n] = bias[wc * 128 + n * 16 + i];

    float* ob = out + (size_t)b * (256 * 256);
#pragma unroll
    for (int r = 0; r < 4; ++r) {
        const int row = n0 + wr * 16 + g * 4 + r;
#pragma unroll
        for (int n = 0; n < 8; ++n) {
            float v = acc[n][r] + biasf[n];
            v = (v >= 0.f) ? v : 0.2f * v;
            __builtin_nontemporal_store(v, &ob[row * 256 + wc * 128 + n * 16 + i]);
        }
    }
}

extern "C" void kernel_launch(void* const* d_in, const int* in_sizes, int n_in,
                              void* d_out, int out_size, void* d_ws, size_t ws_size,
                              hipStream_t stream) {
    const float* x    = (const float*)d_in[0];
    const int*   idx  = (const int*)d_in[1];
    const float* w    = (const float*)d_in[2];
    const float* bias = (const float*)d_in[3];
    float*       out  = (float*)d_out;
    (void)d_ws; (void)ws_size; (void)n_in; (void)out_size;

    const int B = in_sizes[1];          // 2048
    dim3 grid((unsigned)(B * 4)), block(512);
    hipLaunchKernelGGL(argemm_kernel, grid, block, 0, stream, x, idx, w, bias, out);
}

// Round 15
// 248.082 us; speedup vs baseline: 1.9850x; 1.2211x over previous
//
#include <hip/hip_runtime.h>
#include <hip/hip_bf16.h>

// AdaptiveReLULayer: out[b,n,o] = leaky( sum_i x[b,n,i] * weight[idx[b],i,o] + bias[o], 0.2 )
// B=2048, N=256, IN=256, OUT=256, C=1024.  f32 I/O; bf16 MFMA, f32 accum.
//
// R17 = R11 VERBATIM (the 248.5us session best), reverting R16 per its
// pre-commitment (>=260 -> revert and declare).
// Final ledger (15 variants): the two real binders were LDS bank conflicts
// (25M cycles -> 0 via the R7-measured bbyte layout) and cache pollution
// (nontemporal x-loads / out-stores), worth -16% together.  All other axes
// -- x pattern, prefetch depth, barrier removal, w-fabric reduction, block
// stagger, persistent blocks, TLP doubling -- measured null or negative.
// Residual: 1.07GB HBM @ 4.3 of 6.3 TB/s + 2.1GB w L2-fabric traffic
// (~12.8 TB/s aggregate TCC service) = the service wall for this mixed
// gather/compute/store shape at source level.
//
// Structure: tile 64 rows x 256 o per block (grid = 2048*4), 256 thr/4 waves.
//   * A (x): full 64x256 panel staged ONCE in prologue (nt, sequential 1KB
//     row reads) -> bf16 swizzled LDS panel 32KB; zero x-HBM on K-rounds.
//   * B (w): depth-2 reg-staged named sets (anti-sinking sched_barriers),
//     cvt bf16 -> zero-conflict bbyte B^T LDS, double-buffered 2x16KB.
//   * one lgkm+s_barrier per K-round; nt f32 stores; XCD-chunked swizzle.

#define K_DIM 256
#define O_DIM 256
#define BK 32

typedef __attribute__((ext_vector_type(8))) __bf16 bf16x8;
typedef __attribute__((ext_vector_type(4))) float f32x4;
typedef __attribute__((ext_vector_type(4))) unsigned int u32x4;
typedef __attribute__((ext_vector_type(2))) unsigned int u32x2;

__device__ __forceinline__ f32x4 MFMA(u32x4 a, u32x4 b, f32x4 c) {
    return __builtin_amdgcn_mfma_f32_16x16x32_bf16(
        __builtin_bit_cast(bf16x8, a), __builtin_bit_cast(bf16x8, b), c, 0, 0, 0);
}

__device__ __forceinline__ unsigned pk2(float a, float b) {
    __hip_bfloat16 ha = __float2bfloat16(a);
    __hip_bfloat16 hb = __float2bfloat16(b);
    unsigned short sa, sb;
    __builtin_memcpy(&sa, &ha, 2);
    __builtin_memcpy(&sb, &hb, 2);
    return (unsigned)sa | ((unsigned)sb << 16);
}

// B^T tile byte offset for (o 0..255, p 0..31): 128 row-pairs x 128B.
// Measured ZERO bank conflicts (R7/R11) for both the u32x4 staging writes
// (o-quad/p-octet pattern) and the u32x4 frag reads (col = base+n*16+i).
__device__ __forceinline__ int bbyte(int o, int p) {
    const int rp  = o >> 1;
    const int raw = ((o & 1) << 2) | (p >> 3);
    const int key = (rp ^ (o >> 4)) & 7;
    return rp * 128 + ((raw ^ key) << 4) + ((p & 7) << 1);
}

__global__ __launch_bounds__(256) void argemm_kernel(
    const float* __restrict__ x,
    const int* __restrict__ idx,
    const float* __restrict__ w,
    const float* __restrict__ bias,
    float* __restrict__ out)
{
    __shared__ __align__(16) char lds[65536];  // A panel 32KB | B^T dbuf 2x16KB

    const int tid = threadIdx.x;
    const int l   = tid & 63;
    const int wid = tid >> 6;
    const int wr  = wid >> 1;   // 32-row half of the 64-row tile
    const int wc  = wid & 1;    // 128-col half of the 256-col tile

    // XCD-chunked swizzle: the 4 row-tiles of one b are logically adjacent ->
    // same XCD -> w[c] shared in that XCD's L2.
    const unsigned bid     = blockIdx.x;
    const unsigned chunk   = gridDim.x >> 3;
    const unsigned logical = (bid & 7u) * chunk + (bid >> 3);
    const int b  = (int)(logical >> 2);
    const int n0 = (int)(logical & 3u) * 64;

    const int g = l >> 4;   // 0..3 (k-subgroup)
    const int i = l & 15;   // 0..15

    const int c = idx[b];
    const float* xb = x + (size_t)b * (256 * 256);
    const float* wb = w + (size_t)c * (256 * 256);

    // ---- B staging maps (R7's measured-zero shape) ----
    const int q   = tid & 63;        // o-quad: cols q*4 .. q*4+3
    const int oct = tid >> 6;        // p-octet: p = oct*8 .. oct*8+7
    const float* wp = wb + (size_t)(oct * 8) * O_DIM + q * 4;
    int bW[4];
#pragma unroll
    for (int j = 0; j < 4; ++j)
        bW[j] = bbyte(q * 4 + j, oct * 8);

    // ---- fragment read addresses ----
    int bR[8];
#pragma unroll
    for (int n = 0; n < 8; ++n)
        bR[n] = bbyte(wc * 128 + n * 16 + i, g * 8);
    int aRow[2], aKey[2];
#pragma unroll
    for (int m = 0; m < 2; ++m) {
        const int r = wr * 32 + m * 16 + i;
        aRow[m] = r * 512;
        aKey[m] = r & 31;
    }

    // ---- two named B staging sets: tile T -> set T&1 ----
    f32x4 rb[2][8];   // [set][e]: k-row = T*32 + oct*8 + e

    auto issueB = [&](int t, int s) {
#pragma unroll
        for (int e = 0; e < 8; ++e)
            rb[s][e] = *(const f32x4*)(wp + (size_t)(t * BK + e) * O_DIM);
    };
    auto flushB = [&](int T, int s) {
        char* base = (char*)lds + 32768 + (T & 1) * 16384;
#pragma unroll
        for (int j = 0; j < 4; ++j) {
            u32x4 pq;                                   // 8 bf16, p ascending
            pq.x = pk2(rb[s][0][j], rb[s][1][j]);
            pq.y = pk2(rb[s][2][j], rb[s][3][j]);
            pq.z = pk2(rb[s][4][j], rb[s][5][j]);
            pq.w = pk2(rb[s][6][j], rb[s][7][j]);
            *(u32x4*)(base + bW[j]) = pq;
        }
    };

    // ---- prologue: B tiles 0,1 in flight; A panel staged (sequential, nt) ----
    issueB(0, 0);
    __builtin_amdgcn_sched_barrier(0);
    issueB(1, 1);
    __builtin_amdgcn_sched_barrier(0);

    // A: wave stages rows wid*16 .. wid*16+16; one full 1KB row per instr.
    {
        const float* xw = xb + (n0 + wid * 16) * 256 + l * 4;
        const int csw = l >> 1;            // k-chunk this lane holds
        const int sub = (l & 1) * 8;
        f32x4 xa[8];
#pragma unroll
        for (int s2 = 0; s2 < 2; ++s2) {
#pragma unroll
            for (int j = 0; j < 8; ++j)
                xa[j] = __builtin_nontemporal_load(
                    (const f32x4*)(xw + (s2 * 8 + j) * 256));
            __builtin_amdgcn_sched_barrier(0);
#pragma unroll
            for (int j = 0; j < 8; ++j) {
                const int r = wid * 16 + s2 * 8 + j;
                u32x2 p;
                p.x = pk2(xa[j].x, xa[j].y);
                p.y = pk2(xa[j].z, xa[j].w);
                *(u32x2*)((char*)lds + r * 512 + ((csw ^ (r & 31)) << 4) + sub) = p;
            }
        }
    }

    flushB(0, 0);
    issueB(2, 0);
    __builtin_amdgcn_sched_barrier(0);
    asm volatile("s_waitcnt lgkmcnt(0)" ::: "memory");
    __builtin_amdgcn_sched_barrier(0);
    __builtin_amdgcn_s_barrier();

    f32x4 acc[2][8];
#pragma unroll
    for (int m = 0; m < 2; ++m)
#pragma unroll
        for (int n = 0; n < 8; ++n)
            acc[m][n] = (f32x4){0.f, 0.f, 0.f, 0.f};

    // ---- K loop: 8 rounds; rounds touch only LDS (A) and L2/L3-resident w (B) ----
#pragma unroll
    for (int t = 0; t < 8; ++t) {
        const char* bbuf = (const char*)lds + 32768 + (t & 1) * 16384;

        u32x4 af[2];
#pragma unroll
        for (int m = 0; m < 2; ++m)
            af[m] = *(const u32x4*)((const char*)lds + aRow[m]
                                    + (((t * 4 + g) ^ aKey[m]) << 4));
#pragma unroll
        for (int n = 0; n < 8; ++n) {
            const u32x4 bq = *(const u32x4*)(bbuf + bR[n]);
#pragma unroll
            for (int m = 0; m < 2; ++m)
                acc[m][n] = MFMA(af[m], bq, acc[m][n]);
        }

        if (t < 7) {
            flushB(t + 1, (t + 1) & 1);   // loads issued 2 rounds ago
            if (t < 5) {
                issueB(t + 3, (t + 1) & 1);
                __builtin_amdgcn_sched_barrier(0);   // forbid load sinking (R5/R7 lesson)
            }
            asm volatile("s_waitcnt lgkmcnt(0)" ::: "memory");
            __builtin_amdgcn_sched_barrier(0);
            __builtin_amdgcn_s_barrier();
        }
    }

    // ---- epilogue: bias + LeakyReLU(0.2), nontemporal f32 store ----
    float biasf[8];
#pragma unroll
    for (int n = 0; n < 8; ++n)
        biasf[n] = bias[wc * 128 + n * 16 + i];

    float* ob = out + (size_t)b * (256 * 256);
#pragma unroll
    for (int m = 0; m < 2; ++m) {
#pragma unroll
        for (int r = 0; r < 4; ++r) {
            const int row = n0 + wr * 32 + m * 16 + g * 4 + r;
#pragma unroll
            for (int n = 0; n < 8; ++n) {
                float v = acc[m][n][r] + biasf[n];
                v = (v >= 0.f) ? v : 0.2f * v;
                __builtin_nontemporal_store(
                    v, &ob[row * 256 + wc * 128 + n * 16 + i]);
            }
        }
    }
}

extern "C" void kernel_launch(void* const* d_in, const int* in_sizes, int n_in,
                              void* d_out, int out_size, void* d_ws, size_t ws_size,
                              hipStream_t stream) {
    const float* x    = (const float*)d_in[0];
    const int*   idx  = (const int*)d_in[1];
    const float* w    = (const float*)d_in[2];
    const float* bias = (const float*)d_in[3];
    float*       out  = (float*)d_out;
    (void)d_ws; (void)ws_size; (void)n_in; (void)out_size;

    const int B = in_sizes[1];          // 2048
    dim3 grid((unsigned)(B * 4)), block(256);
    hipLaunchKernelGGL(argemm_kernel, grid, block, 0, stream, x, idx, w, bias, out);
}